// Round 1
// 1132.036 us; speedup vs baseline: 1.1871x; 1.1871x over previous
//
#include <hip/hip_runtime.h>

// LowRankKVCache: out = X @ Vt^T @ Vt where Vt = top-64 eigenvectors of X^T X.
// 64 independent 2048x128 fp32 matrices (B*H = 4*16).
//
// Round 5: odd-even (Brent-Luk) one-sided Jacobi with REGISTER-RESIDENT
// columns. 64 groups x 8 lanes; group g owns column slots (2g, 2g+1) in
// VGPRs. A-steps (pairs 2g,2g+1) are fully local: no LDS, no barrier.
// B-steps (pairs 2g+1,2g+2) hand one column to the right neighbor through a
// 64 KB LDS exchange buffer: publish even col -> bar -> read neighbor,
// rotate, write updated neighbor col -> bar -> read back my even col.
// Per 2 steps: 16 b128 LDS ops/lane (was 32), 2 barriers over 8 waves
// (was 2 over 16). Always-swap after each pairing makes the odd-even
// schedule cover all C(128,2) pairs once per 128-step sweep.
//
// ws layout (bytes):
//   [0, 4M)        G      (64 x 128x128 f32)   -- dead after jacobi
//   [4M, 8M)       Vfull  (64 x 128x128 f32)   -- dead after select_k
//   [8M, 8M+32K)   normg  (64 x 128 f32)       -- dead after select_k
//   [32M, 34M)     Vt     (64 x 64x128 f32)
//   [0, 32M)       W      (64 x 2048x64 f32)   -- overlays dead G/Vfull/normg
// total requirement: 34 MB of d_ws.

#define NM 64
#define SEQ 2048
#define DD 128
#define RR 64
#define NSWEEP 7
#define NROUND (NSWEEP * 64)  // one round = A-step + B-step; 64 rounds/sweep

#define OFF_VFULL (4194304ULL)
#define OFF_NORM  (8388608ULL)
#define OFF_VT    (33554432ULL)

__device__ __forceinline__ float dot4(float4 a, float4 b) {
  return a.x * b.x + a.y * b.y + a.z * b.z + a.w * b.w;
}

// DPP butterfly add over aligned lane groups (VALU pipe -- keeps the DS pipe
// free for the column traffic). CTRL: 0xB1=quad xor1, 0x4E=quad xor2,
// 0x141=row_half_mirror (8-lane).
template <int CTRL>
__device__ __forceinline__ float dpp_add(float x) {
  int y = __builtin_amdgcn_update_dpp(0, __float_as_int(x), CTRL, 0xf, 0xf, true);
  return x + __int_as_float(y);
}
__device__ __forceinline__ float red8(float x) {  // sum over aligned 8 lanes
  x = dpp_add<0xB1>(x);
  x = dpp_add<0x4E>(x);
  x = dpp_add<0x141>(x);
  return x;
}

// Jacobi rotation angle from the pair's 2x2 Gram. Identity when converged
// (still swapped by the caller -- the odd-even schedule needs always-swap).
__device__ __forceinline__ void jrot(float app, float apq, float aqq,
                                     float& c, float& s) {
  c = 1.f;
  s = 0.f;
  if (apq * apq > 1e-9f * app * aqq) {
    float tau = (aqq - app) / (2.f * apq);
    float tv = 1.f / (fabsf(tau) + sqrtf(1.f + tau * tau));
    tv = tau < 0.f ? -tv : tv;
    c = 1.f / sqrtf(1.f + tv * tv);
    s = tv * c;
  }
}

__device__ __forceinline__ void rot4(float c, float s, float4 p, float4 q,
                                     float4& np, float4& nq) {
  np.x = c * p.x - s * q.x;  nq.x = s * p.x + c * q.x;
  np.y = c * p.y - s * q.y;  nq.y = s * p.y + c * q.y;
  np.z = c * p.z - s * q.z;  nq.z = s * p.z + c * q.z;
  np.w = c * p.w - s * q.w;  nq.w = s * p.w + c * q.w;
}

// ---------------- K1: Gram G[m] = X[m]^T X[m] ----------------
__global__ __launch_bounds__(256) void gram_k(const float* __restrict__ X,
                                              float* __restrict__ G) {
  const int m = blockIdx.y;
  const int r0 = blockIdx.x * 32;  // G row tile (== X column tile)
  const int tid = threadIdx.x;
  __shared__ __align__(16) float Xs[64][128];  // 32 KB
  const float* Xm = X + (size_t)m * SEQ * DD;
  const int ti = tid >> 5;  // 0..7  -> G rows r0+4ti..+3
  const int tj = tid & 31;  // 0..31 -> G cols 4tj..+3
  float acc[4][4];
#pragma unroll
  for (int a = 0; a < 4; ++a)
#pragma unroll
    for (int b = 0; b < 4; ++b) acc[a][b] = 0.f;

  for (int s0 = 0; s0 < SEQ; s0 += 64) {
    __syncthreads();
    for (int t = tid; t < 2048; t += 256) {  // 64 rows x 32 float4
      int s = t >> 5, c4 = t & 31;
      *(float4*)&Xs[s][c4 * 4] =
          *(const float4*)&Xm[(size_t)(s0 + s) * DD + c4 * 4];
    }
    __syncthreads();
#pragma unroll 4
    for (int s = 0; s < 64; ++s) {
      float4 av = *(const float4*)&Xs[s][r0 + 4 * ti];
      float4 bv = *(const float4*)&Xs[s][4 * tj];
      acc[0][0] += av.x * bv.x; acc[0][1] += av.x * bv.y;
      acc[0][2] += av.x * bv.z; acc[0][3] += av.x * bv.w;
      acc[1][0] += av.y * bv.x; acc[1][1] += av.y * bv.y;
      acc[1][2] += av.y * bv.z; acc[1][3] += av.y * bv.w;
      acc[2][0] += av.z * bv.x; acc[2][1] += av.z * bv.y;
      acc[2][2] += av.z * bv.z; acc[2][3] += av.z * bv.w;
      acc[3][0] += av.w * bv.x; acc[3][1] += av.w * bv.y;
      acc[3][2] += av.w * bv.z; acc[3][3] += av.w * bv.w;
    }
  }
  float* Gm = G + (size_t)m * DD * DD;
#pragma unroll
  for (int a = 0; a < 4; ++a) {
    float4 v = make_float4(acc[a][0], acc[a][1], acc[a][2], acc[a][3]);
    *(float4*)&Gm[(size_t)(r0 + 4 * ti + a) * DD + 4 * tj] = v;
  }
}

// ---------------- K2: odd-even one-sided Jacobi, columns in registers ------
// 512 threads = 64 groups x 8 lanes. Group g owns slots (2g, 2g+1).
// Lane l holds float4 indices {l, l+8, l+16, l+24} of each 128-float column
// (every aligned 8-lane octet touches a contiguous 128 B of LDS -> no bank
// conflicts). Exchange buffer: column slot s lives at xch[s*32 .. s*32+31].
__global__ __launch_bounds__(512) void jacobi_oe_k(const float* __restrict__ G,
                                                   float* __restrict__ Vfull,
                                                   float* __restrict__ normg) {
  const int m = blockIdx.x;
  const int tid = threadIdx.x;
  const int g = tid >> 3;  // group 0..63
  const int l = tid & 7;   // lane in group
  __shared__ float4 xch[DD * 32];  // 64 KB

  // G is symmetric: column j of G == row j of G -> transpose-free load.
  const float4* Gm4 = (const float4*)(G + (size_t)m * DD * DD);
  float4 ce[4], co[4];  // even slot (2g), odd slot (2g+1)
#pragma unroll
  for (int j = 0; j < 4; ++j) {
    ce[j] = Gm4[(size_t)(2 * g) * 32 + l + 8 * j];
    co[j] = Gm4[(size_t)(2 * g + 1) * 32 + l + 8 * j];
  }
  const bool hasR = (g < 63);  // right B-pair (2g+1, 2g+2) exists
  const bool hasL = (g > 0);   // even col participates in left B-pair
  float4* homeE = &xch[(2 * g) * 32];        // my even column's LDS home
  float4* homeR = &xch[(2 * g + 2) * 32];    // right neighbor's even home

  for (int round = 0; round < NROUND; ++round) {
    // ---- A-step: local pair (2g, 2g+1), register-only, no barrier ----
    {
      float app = 0.f, apq = 0.f, aqq = 0.f;
#pragma unroll
      for (int j = 0; j < 4; ++j) {
        app += dot4(ce[j], ce[j]);
        apq += dot4(ce[j], co[j]);
        aqq += dot4(co[j], co[j]);
      }
      app = red8(app); apq = red8(apq); aqq = red8(aqq);
      float c, s;
      jrot(app, apq, aqq, c, s);
#pragma unroll
      for (int j = 0; j < 4; ++j) {
        float4 np, nq;
        rot4(c, s, ce[j], co[j], np, nq);
        ce[j] = nq;  // always-swap: even slot <- nq
        co[j] = np;  //               odd slot  <- np
      }
    }
    // ---- B-step phase 1: publish my even column (post-A value) ----
    if (hasL) {
#pragma unroll
      for (int j = 0; j < 4; ++j) homeE[l + 8 * j] = ce[j];
    }
    __syncthreads();
    // ---- B-step phase 2: rotate right pair (2g+1 local, 2g+2 from LDS),
    //      hand the updated neighbor column back through its home. ----
    if (hasR) {
      float4 r[4];
#pragma unroll
      for (int j = 0; j < 4; ++j) r[j] = homeR[l + 8 * j];
      float app = 0.f, apq = 0.f, aqq = 0.f;
#pragma unroll
      for (int j = 0; j < 4; ++j) {
        app += dot4(co[j], co[j]);
        apq += dot4(co[j], r[j]);
        aqq += dot4(r[j], r[j]);
      }
      app = red8(app); apq = red8(apq); aqq = red8(aqq);
      float c, s;
      jrot(app, apq, aqq, c, s);
#pragma unroll
      for (int j = 0; j < 4; ++j) {
        float4 np, nq;
        rot4(c, s, co[j], r[j], np, nq);
        homeR[l + 8 * j] = np;  // slot 2g+2 <- np (handoff, swap)
        co[j] = nq;             // slot 2g+1 <- nq (swap)
      }
    }
    __syncthreads();
    // ---- B-step phase 3: receive my updated even column ----
    if (hasL) {
#pragma unroll
      for (int j = 0; j < 4; ++j) ce[j] = homeE[l + 8 * j];
    }
  }

  // Emit all 128 (unnormalized) eigenvector candidates + squared norms.
  float ne = 0.f, no = 0.f;
#pragma unroll
  for (int j = 0; j < 4; ++j) {
    ne += dot4(ce[j], ce[j]);
    no += dot4(co[j], co[j]);
  }
  ne = red8(ne);
  no = red8(no);
  float4* Ve = (float4*)(Vfull + ((size_t)m * DD + 2 * g) * DD);
  float4* Vo = (float4*)(Vfull + ((size_t)m * DD + 2 * g + 1) * DD);
#pragma unroll
  for (int j = 0; j < 4; ++j) {
    Ve[l + 8 * j] = ce[j];
    Vo[l + 8 * j] = co[j];
  }
  if (l == 0) {
    normg[m * DD + 2 * g] = ne;      // |col|^2 = lambda^2
    normg[m * DD + 2 * g + 1] = no;
  }
}

// ---------------- K2b: rank-select top-64 columns, normalize -> Vt ---------
__global__ __launch_bounds__(128) void select_k(const float* __restrict__ Vfull,
                                                const float* __restrict__ normg,
                                                float* __restrict__ Vt) {
  const int m = blockIdx.x;
  const int t = threadIdx.x;  // 0..127
  __shared__ float n[DD];
  __shared__ int inv[RR];
  __shared__ float scl[RR];
  n[t] = normg[m * DD + t];
  __syncthreads();
  float nt = n[t];
  int rk = 0;
  for (int k = 0; k < DD; ++k) {
    float nk = n[k];
    rk += ((nk > nt) || (nk == nt && k < t)) ? 1 : 0;
  }
  if (rk < RR) { inv[rk] = t; scl[rk] = 1.f / sqrtf(nt); }
  __syncthreads();
  for (int r = 0; r < RR; ++r) {
    Vt[((size_t)m * RR + r) * DD + t] =
        Vfull[((size_t)m * DD + inv[r]) * DD + t] * scl[r];
  }
}

// ---------------- K4: W = X @ Vt^T  (2048x64 per matrix) -------------------
__global__ __launch_bounds__(256) void gemm1_k(const float* __restrict__ X,
                                               const float* __restrict__ Vt,
                                               float* __restrict__ W) {
  const int m = blockIdx.y;
  const int s0 = blockIdx.x * 32;
  const int tid = threadIdx.x;
  __shared__ __align__(16) float VtT[128 * 68];  // [c][r], 34.8 KB
  __shared__ __align__(16) float Xs[32 * 132];   // padded, 16.9 KB
  const float* Vm = Vt + (size_t)m * RR * DD;
  for (int t = tid; t < RR * DD; t += 256) {
    int r = t >> 7, c = t & 127;
    VtT[c * 68 + r] = Vm[t];
  }
  const float* Xm = X + ((size_t)m * SEQ + s0) * DD;
  for (int t = tid; t < 1024; t += 256) {  // 32 rows x 32 float4
    int s = t >> 5, c4 = t & 31;
    *(float4*)&Xs[s * 132 + 4 * c4] = *(const float4*)&Xm[(size_t)s * DD + 4 * c4];
  }
  __syncthreads();
  const int ti = tid >> 4;  // 0..15 -> rows 2ti, 2ti+1
  const int tj = tid & 15;  // cols 4tj..+3
  float acc[2][4] = {{0.f, 0.f, 0.f, 0.f}, {0.f, 0.f, 0.f, 0.f}};
#pragma unroll 4
  for (int k = 0; k < DD; ++k) {
    float a0 = Xs[(2 * ti) * 132 + k];
    float a1 = Xs[(2 * ti + 1) * 132 + k];
    float4 bv = *(float4*)&VtT[k * 68 + 4 * tj];
    acc[0][0] += a0 * bv.x; acc[0][1] += a0 * bv.y;
    acc[0][2] += a0 * bv.z; acc[0][3] += a0 * bv.w;
    acc[1][0] += a1 * bv.x; acc[1][1] += a1 * bv.y;
    acc[1][2] += a1 * bv.z; acc[1][3] += a1 * bv.w;
  }
  float* Wm = W + ((size_t)m * SEQ + s0) * RR;
#pragma unroll
  for (int d = 0; d < 2; ++d) {
    float4 v = make_float4(acc[d][0], acc[d][1], acc[d][2], acc[d][3]);
    *(float4*)&Wm[(size_t)(2 * ti + d) * RR + 4 * tj] = v;
  }
}

// ---------------- K5: out = W @ Vt  (2048x128 per matrix) ------------------
__global__ __launch_bounds__(256) void gemm2_k(const float* __restrict__ W,
                                               const float* __restrict__ Vt,
                                               float* __restrict__ out) {
  const int m = blockIdx.y;
  const int s0 = blockIdx.x * 32;
  const int tid = threadIdx.x;
  __shared__ __align__(16) float Vts[64 * 132];  // 33.8 KB
  __shared__ __align__(16) float Ws[32 * 68];    // 8.7 KB
  const float* Vm = Vt + (size_t)m * RR * DD;
  for (int t = tid; t < 2048; t += 256) {  // 64 rows x 32 float4
    int r = t >> 5, c4 = t & 31;
    *(float4*)&Vts[r * 132 + 4 * c4] = *(const float4*)&Vm[(size_t)r * DD + 4 * c4];
  }
  const float* Wm = W + ((size_t)m * SEQ + s0) * RR;
  for (int t = tid; t < 512; t += 256) {  // 32 rows x 16 float4
    int s = t >> 4, c4 = t & 15;
    *(float4*)&Ws[s * 68 + 4 * c4] = *(const float4*)&Wm[(size_t)s * RR + 4 * c4];
  }
  __syncthreads();
  const int ti = tid >> 5;  // 0..7 -> rows 4ti..+3
  const int tj = tid & 31;  // cols 4tj..+3
  float acc[4][4] = {{0.f,0.f,0.f,0.f},{0.f,0.f,0.f,0.f},
                     {0.f,0.f,0.f,0.f},{0.f,0.f,0.f,0.f}};
#pragma unroll 4
  for (int k = 0; k < RR; ++k) {
    float4 bv = *(float4*)&Vts[k * 132 + 4 * tj];
    float a0 = Ws[(4 * ti + 0) * 68 + k];
    float a1 = Ws[(4 * ti + 1) * 68 + k];
    float a2 = Ws[(4 * ti + 2) * 68 + k];
    float a3 = Ws[(4 * ti + 3) * 68 + k];
    acc[0][0] += a0 * bv.x; acc[0][1] += a0 * bv.y;
    acc[0][2] += a0 * bv.z; acc[0][3] += a0 * bv.w;
    acc[1][0] += a1 * bv.x; acc[1][1] += a1 * bv.y;
    acc[1][2] += a1 * bv.z; acc[1][3] += a1 * bv.w;
    acc[2][0] += a2 * bv.x; acc[2][1] += a2 * bv.y;
    acc[2][2] += a2 * bv.z; acc[2][3] += a2 * bv.w;
    acc[3][0] += a3 * bv.x; acc[3][1] += a3 * bv.y;
    acc[3][2] += a3 * bv.z; acc[3][3] += a3 * bv.w;
  }
  float* Om = out + ((size_t)m * SEQ + s0) * DD;
#pragma unroll
  for (int d = 0; d < 4; ++d) {
    float4 v = make_float4(acc[d][0], acc[d][1], acc[d][2], acc[d][3]);
    *(float4*)&Om[(size_t)(4 * ti + d) * DD + 4 * tj] = v;
  }
}

extern "C" void kernel_launch(void* const* d_in, const int* in_sizes, int n_in,
                              void* d_out, int out_size, void* d_ws, size_t ws_size,
                              hipStream_t stream) {
  (void)in_sizes; (void)n_in; (void)out_size; (void)ws_size;
  const float* X = (const float*)d_in[0];  // rank (d_in[1]) is fixed at 64
  float* out = (float*)d_out;
  char* ws = (char*)d_ws;
  float* G = (float*)ws;
  float* Vfull = (float*)(ws + OFF_VFULL);
  float* normg = (float*)(ws + OFF_NORM);
  float* Vt = (float*)(ws + OFF_VT);
  float* W = (float*)ws;  // overlays dead G/Vfull/normg

  gram_k<<<dim3(4, NM), 256, 0, stream>>>(X, G);
  jacobi_oe_k<<<NM, 512, 0, stream>>>(G, Vfull, normg);
  select_k<<<NM, 128, 0, stream>>>(Vfull, normg, Vt);
  gemm1_k<<<dim3(SEQ / 32, NM), 256, 0, stream>>>(X, Vt, W);
  gemm2_k<<<dim3(SEQ / 32, NM), 256, 0, stream>>>(W, Vt, out);
}